// Round 3
// baseline (616.043 us; speedup 1.0000x reference)
//
#include <hip/hip_runtime.h>
#include <hip/hip_bf16.h>
#include <stdint.h>

typedef __bf16 bf16_t;
typedef bf16_t bf16x8 __attribute__((ext_vector_type(8)));
typedef bf16_t bf16x4 __attribute__((ext_vector_type(4)));
typedef float  f32x4  __attribute__((ext_vector_type(4)));

#define SLEN 2048
#define NHEAD 16

// ---------------- workspace layout (bytes) ----------------
static const size_t OFF_XB    = 0;          // x bf16            (2048*2048*2 = 8388608)
static const size_t OFF_WAT   = 8388608;    // [w_qa|w_kva]^T    (1408*2048*2 = 5767168)
static const size_t OFF_WQBT  = 14155776;   // w_qb^T            (3072*768*2  = 4718592)
static const size_t OFF_WKVBT = 18874368;   // w_kvb^T           (4096*512*2  = 4194304)
static const size_t OFF_WOT   = 23068672;   // w_o^T             (2048*2048*2 = 8388608)
static const size_t OFF_QKVA  = 31457280;   // qkv_a fp32        (2048*1408*4 = 11534336)
static const size_t OFF_QAN   = 42991616;   // q_a normed bf16   (2048*768*2  = 3145728)
static const size_t OFF_CKVN  = 46137344;   // c_kv normed bf16  (2048*512*2  = 2097152)
static const size_t OFF_COS   = 48234496;   // cos table f32     (2048*64*4   = 524288)
static const size_t OFF_SIN   = 48758784;   // sin table f32     (524288)
static const size_t OFF_QFULL = 49283072;   // q_full bf16 (H,S,192) (12582912)
static const size_t OFF_KFULL = 61865984;   // k_full bf16 (H,S,192) (12582912)
static const size_t OFF_VT    = 74448896;   // v^T bf16 (H,128,S)    (8388608)
static const size_t OFF_ATTN  = 82837504;   // attn out bf16 (S,2048)(8388608)
// total 91,226,112 B

__device__ __forceinline__ void gll16(const void* g, void* l) {
  __builtin_amdgcn_global_load_lds((__attribute__((address_space(1))) void*)g,
                                   (__attribute__((address_space(3))) void*)l,
                                   16, 0, 0);
}

// ---------------- fp32 -> bf16 elementwise ----------------
__global__ __launch_bounds__(256) void k_cvt_bf16(const float* __restrict__ in,
                                                  bf16_t* __restrict__ out, int n) {
  int i = (blockIdx.x * 256 + threadIdx.x) * 8;
  if (i >= n) return;
  f32x4 a = *(const f32x4*)&in[i];
  f32x4 b = *(const f32x4*)&in[i + 4];
  bf16x8 o;
  #pragma unroll
  for (int j = 0; j < 4; j++) { o[j] = (bf16_t)a[j]; o[j + 4] = (bf16_t)b[j]; }
  *(bf16x8*)&out[i] = o;
}

// ---------------- transpose + convert: w(K,N) f32 -> wT(Nout,K) bf16, rows>=N zero ----------------
__global__ __launch_bounds__(256) void k_transpose_cvt(const float* __restrict__ in,
                                                       bf16_t* __restrict__ out,
                                                       int K, int N, int Nout) {
  __shared__ float tile[32][33];
  const int nt = blockIdx.x, kt = blockIdx.y;
  const int t = threadIdx.x;
  const int r = t >> 3, c4 = (t & 7) * 4;
  const int gk = kt * 32 + r;
  #pragma unroll
  for (int j = 0; j < 4; j++) {
    int gn = nt * 32 + c4 + j;
    tile[r][c4 + j] = (gn < N) ? in[(size_t)gk * N + gn] : 0.f;
  }
  __syncthreads();
  bf16x4 o;
  #pragma unroll
  for (int j = 0; j < 4; j++) o[j] = (bf16_t)tile[c4 + j][r];
  *(bf16x4*)&out[(size_t)(nt * 32 + r) * K + kt * 32 + c4] = o;
}

// ---------------- rope tables: cos/sin (S,64) f32 ----------------
__global__ __launch_bounds__(256) void k_rope_tables(float* __restrict__ cosT,
                                                     float* __restrict__ sinT) {
  int i = blockIdx.x * 256 + threadIdx.x;          // S*64 total
  int s = i >> 6, d = i & 63;
  float invf = powf(10000.f, -(float)(2 * (d & 31)) / 64.f);
  float ang = (float)s * invf;
  cosT[i] = cosf(ang);
  sinT[i] = sinf(ang);
}

// ---------------- generic 128x128 bf16 MFMA GEMM, B^T input ----------------
// EPI 0: fp32 store to Cf (stride N)
// EPI 1: q epilogue: per col c: h=c/192, d=c%192; rope on d>=128; -> O1 = qfull (H,S,192)
// EPI 2: kv epilogue: h=c>>8, w=c&255; w<128 -> O1=kfull(H,S,192) nope part; else O2=vT(H,128,S)
template<int EPI>
__global__ __launch_bounds__(256) void k_gemm(const bf16_t* __restrict__ A,
                                              const bf16_t* __restrict__ Bt,
                                              int M, int N, int K,
                                              float* __restrict__ Cf,
                                              bf16_t* __restrict__ O1,
                                              bf16_t* __restrict__ O2,
                                              const float* __restrict__ cosT,
                                              const float* __restrict__ sinT) {
  __shared__ __align__(16) bf16_t sA[128 * 32];
  __shared__ __align__(16) bf16_t sB[128 * 32];
  const int t = threadIdx.x;
  const int lane = t & 63, wave = t >> 6;
  const int l15 = lane & 15, l4 = lane >> 4;
  const int wr = wave >> 1, wc = wave & 1;
  const int rowBase = blockIdx.y * 128, colBase = blockIdx.x * 128;

  f32x4 acc[4][4] = {};

  const int c0 = t, c1 = t + 256;
  const size_t aoff0 = (size_t)(rowBase + (c0 >> 2)) * K + (c0 & 3) * 8;
  const size_t aoff1 = (size_t)(rowBase + (c1 >> 2)) * K + (c1 & 3) * 8;
  const size_t boff0 = (size_t)(colBase + (c0 >> 2)) * K + (c0 & 3) * 8;
  const size_t boff1 = (size_t)(colBase + (c1 >> 2)) * K + (c1 & 3) * 8;

  for (int k0 = 0; k0 < K; k0 += 32) {
    gll16(A + aoff0 + k0, sA + wave * 512);
    gll16(A + aoff1 + k0, sA + 2048 + wave * 512);
    gll16(Bt + boff0 + k0, sB + wave * 512);
    gll16(Bt + boff1 + k0, sB + 2048 + wave * 512);
    __syncthreads();
    bf16x8 af[4], bfv[4];
    #pragma unroll
    for (int m = 0; m < 4; m++)
      af[m] = *(const bf16x8*)&sA[(wr * 64 + m * 16 + l15) * 32 + l4 * 8];
    #pragma unroll
    for (int n = 0; n < 4; n++)
      bfv[n] = *(const bf16x8*)&sB[(wc * 64 + n * 16 + l15) * 32 + l4 * 8];
    #pragma unroll
    for (int m = 0; m < 4; m++)
      #pragma unroll
      for (int n = 0; n < 4; n++)
        acc[m][n] = __builtin_amdgcn_mfma_f32_16x16x32_bf16(af[m], bfv[n], acc[m][n], 0, 0, 0);
    __syncthreads();
  }

  if (EPI == 0) {
    #pragma unroll
    for (int m = 0; m < 4; m++)
      #pragma unroll
      for (int n = 0; n < 4; n++)
        #pragma unroll
        for (int r = 0; r < 4; r++) {
          int row = rowBase + wr * 64 + m * 16 + l4 * 4 + r;
          int col = colBase + wc * 64 + n * 16 + l15;
          Cf[(size_t)row * N + col] = acc[m][n][r];
        }
  } else if (EPI == 1) {
    #pragma unroll
    for (int m = 0; m < 4; m++)
      #pragma unroll
      for (int n = 0; n < 4; n++) {
        int cb = colBase + wc * 64 + n * 16 + l15;
        int h = cb / 192, d = cb - h * 192;
        #pragma unroll
        for (int r = 0; r < 4; r++) {
          int s = rowBase + wr * 64 + m * 16 + l4 * 4 + r;
          float v = acc[m][n][r];
          float p = __shfl_xor(v, 1);   // pair partner (cols are lane-consecutive)
          float o = v;
          if (d >= 128) {
            int i = d - 128;
            float cs = cosT[s * 64 + i], sn = sinT[s * 64 + i];
            o = (i & 1) ? (v * cs + p * sn) : (v * cs - p * sn);
          }
          O1[((size_t)h * SLEN + s) * 192 + d] = (bf16_t)o;
        }
      }
  } else { // EPI == 2
    #pragma unroll
    for (int m = 0; m < 4; m++)
      #pragma unroll
      for (int n = 0; n < 4; n++) {
        int cb = colBase + wc * 64 + n * 16 + l15;
        int h = cb >> 8, w = cb & 255;
        if (w < 128) {
          #pragma unroll
          for (int r = 0; r < 4; r++) {
            int s = rowBase + wr * 64 + m * 16 + l4 * 4 + r;
            O1[((size_t)h * SLEN + s) * 192 + w] = (bf16_t)acc[m][n][r];
          }
        } else {
          int d = w - 128;
          int s0 = rowBase + wr * 64 + m * 16 + l4 * 4;
          bf16x4 o;
          #pragma unroll
          for (int r = 0; r < 4; r++) o[r] = (bf16_t)acc[m][n][r];
          *(bf16x4*)&O2[((size_t)h * 128 + d) * SLEN + s0] = o;
        }
      }
  }
}

// ---------------- RMSNorm q_a rows (768) -> bf16 ----------------
__global__ __launch_bounds__(256) void k_rmsnorm_q(const float* __restrict__ qkv,
                                                   const float* __restrict__ w,
                                                   bf16_t* __restrict__ out) {
  __shared__ float red[4];
  const int row = blockIdx.x, t = threadIdx.x;
  const float* x = qkv + (size_t)row * 1408;
  float v0 = x[t], v1 = x[t + 256], v2 = x[t + 512];
  float ss = v0 * v0 + v1 * v1 + v2 * v2;
  #pragma unroll
  for (int off = 32; off; off >>= 1) ss += __shfl_down(ss, off);
  if ((t & 63) == 0) red[t >> 6] = ss;
  __syncthreads();
  ss = red[0] + red[1] + red[2] + red[3];
  float rs = rsqrtf(ss * (1.f / 768.f) + 1e-6f);
  out[(size_t)row * 768 + t]       = (bf16_t)(v0 * rs * w[t]);
  out[(size_t)row * 768 + t + 256] = (bf16_t)(v1 * rs * w[t + 256]);
  out[(size_t)row * 768 + t + 512] = (bf16_t)(v2 * rs * w[t + 512]);
}

// ---------------- RMSNorm c_kv rows (512) + k_rope RoPE broadcast ----------------
__global__ __launch_bounds__(256) void k_rmsnorm_kv(const float* __restrict__ qkv,
                                                    const float* __restrict__ w,
                                                    bf16_t* __restrict__ ckvn,
                                                    bf16_t* __restrict__ kfull,
                                                    const float* __restrict__ cosT,
                                                    const float* __restrict__ sinT) {
  __shared__ float red[4];
  const int row = blockIdx.x, t = threadIdx.x;
  const float* x = qkv + (size_t)row * 1408 + 768;
  float v0 = x[t], v1 = x[t + 256];
  float ss = v0 * v0 + v1 * v1;
  #pragma unroll
  for (int off = 32; off; off >>= 1) ss += __shfl_down(ss, off);
  if ((t & 63) == 0) red[t >> 6] = ss;
  __syncthreads();
  ss = red[0] + red[1] + red[2] + red[3];
  float rs = rsqrtf(ss * (1.f / 512.f) + 1e-6f);
  ckvn[(size_t)row * 512 + t]       = (bf16_t)(v0 * rs * w[t]);
  ckvn[(size_t)row * 512 + t + 256] = (bf16_t)(v1 * rs * w[t + 256]);
  if (t < 64) {
    float xv = x[512 + t];
    float xo = x[512 + (t ^ 1)];
    float cs = cosT[row * 64 + t], sn = sinT[row * 64 + t];
    float o = (t & 1) ? (xv * cs + xo * sn) : (xv * cs - xo * sn);
    bf16_t ob = (bf16_t)o;
    for (int h = 0; h < NHEAD; h++)
      kfull[((size_t)h * SLEN + row) * 192 + 128 + t] = ob;
  }
}

// ---------------- causal flash attention ----------------
// grid (32 qblocks, 16 heads), 256 threads = 4 waves, each wave owns 16 q rows.
__global__ __launch_bounds__(256) void k_attn(const bf16_t* __restrict__ qfull,
                                              const bf16_t* __restrict__ kfull,
                                              const bf16_t* __restrict__ vT,
                                              bf16_t* __restrict__ out) {
  __shared__ __align__(16) bf16_t P[4][16][72];   // per-wave P tile, padded
  const int qb = blockIdx.x, h = blockIdx.y;
  const int t = threadIdx.x, lane = t & 63, wave = t >> 6;
  const int l15 = lane & 15, l4 = lane >> 4;
  const int qr0 = qb * 64 + wave * 16;
  const bf16_t* qh = qfull + (size_t)h * SLEN * 192;
  const bf16_t* kh = kfull + (size_t)h * SLEN * 192;
  const bf16_t* vh = vT + (size_t)h * 128 * SLEN;

  bf16x8 qf[6];
  #pragma unroll
  for (int kk = 0; kk < 6; kk++)
    qf[kk] = *(const bf16x8*)&qh[(size_t)(qr0 + l15) * 192 + kk * 32 + l4 * 8];

  f32x4 oacc[8] = {};
  float mrun[4], lrun[4];
  #pragma unroll
  for (int r = 0; r < 4; r++) { mrun[r] = -3e30f; lrun[r] = 0.f; }
  const float scale = 0.0721687836f;  // 1/sqrt(192)
  int rowq[4];
  #pragma unroll
  for (int r = 0; r < 4; r++) rowq[r] = qr0 + l4 * 4 + r;

  for (int kb = 0; kb <= qb; kb++) {
    const int kv0 = kb * 64;
    f32x4 sc[4] = {};
    #pragma unroll
    for (int kk = 0; kk < 6; kk++)
      #pragma unroll
      for (int n = 0; n < 4; n++) {
        bf16x8 bv = *(const bf16x8*)&kh[(size_t)(kv0 + n * 16 + l15) * 192 + kk * 32 + l4 * 8];
        sc[n] = __builtin_amdgcn_mfma_f32_16x16x32_bf16(qf[kk], bv, sc[n], 0, 0, 0);
      }
    float sv[4][4];
    const bool diag = (kb == qb);
    #pragma unroll
    for (int n = 0; n < 4; n++)
      #pragma unroll
      for (int r = 0; r < 4; r++) {
        float v = sc[n][r] * scale;
        if (diag && (kv0 + n * 16 + l15 > rowq[r])) v = -3e30f;
        sv[n][r] = v;
      }
    float fac[4];
    #pragma unroll
    for (int r = 0; r < 4; r++) {
      float rm = fmaxf(fmaxf(sv[0][r], sv[1][r]), fmaxf(sv[2][r], sv[3][r]));
      #pragma unroll
      for (int off = 1; off < 16; off <<= 1) rm = fmaxf(rm, __shfl_xor(rm, off));
      float mn = fmaxf(mrun[r], rm);
      fac[r] = __expf(mrun[r] - mn);
      mrun[r] = mn;
    }
    float psum[4] = {0.f, 0.f, 0.f, 0.f};
    #pragma unroll
    for (int n = 0; n < 4; n++)
      #pragma unroll
      for (int r = 0; r < 4; r++) {
        float p = __expf(sv[n][r] - mrun[r]);
        psum[r] += p;
        P[wave][l4 * 4 + r][n * 16 + l15] = (bf16_t)p;
      }
    #pragma unroll
    for (int r = 0; r < 4; r++) {
      #pragma unroll
      for (int off = 1; off < 16; off <<= 1) psum[r] += __shfl_xor(psum[r], off);
      lrun[r] = lrun[r] * fac[r] + psum[r];
    }
    #pragma unroll
    for (int n8 = 0; n8 < 8; n8++)
      #pragma unroll
      for (int r = 0; r < 4; r++) oacc[n8][r] *= fac[r];
    #pragma unroll
    for (int kk = 0; kk < 2; kk++) {
      bf16x8 pa = *(const bf16x8*)&P[wave][l15][kk * 32 + l4 * 8];
      #pragma unroll
      for (int n8 = 0; n8 < 8; n8++) {
        bf16x8 vb = *(const bf16x8*)&vh[(size_t)(n8 * 16 + l15) * SLEN + kv0 + kk * 32 + l4 * 8];
        oacc[n8] = __builtin_amdgcn_mfma_f32_16x16x32_bf16(pa, vb, oacc[n8], 0, 0, 0);
      }
    }
  }
  #pragma unroll
  for (int n8 = 0; n8 < 8; n8++)
    #pragma unroll
    for (int r = 0; r < 4; r++) {
      int s = qr0 + l4 * 4 + r;
      out[(size_t)s * 2048 + h * 128 + n8 * 16 + l15] = (bf16_t)(oacc[n8][r] / lrun[r]);
    }
}

// ---------------- launcher ----------------
extern "C" void kernel_launch(void* const* d_in, const int* in_sizes, int n_in,
                              void* d_out, int out_size, void* d_ws, size_t ws_size,
                              hipStream_t stream) {
  const float* x     = (const float*)d_in[0];
  const float* w_qa  = (const float*)d_in[1];
  const float* qnw   = (const float*)d_in[2];
  const float* w_qb  = (const float*)d_in[3];
  const float* w_kva = (const float*)d_in[4];
  const float* kvnw  = (const float*)d_in[5];
  const float* w_kvb = (const float*)d_in[6];
  const float* w_o   = (const float*)d_in[7];
  float* out = (float*)d_out;
  char* ws = (char*)d_ws;

  bf16_t* xb    = (bf16_t*)(ws + OFF_XB);
  bf16_t* wat   = (bf16_t*)(ws + OFF_WAT);
  bf16_t* wqbT  = (bf16_t*)(ws + OFF_WQBT);
  bf16_t* wkvbT = (bf16_t*)(ws + OFF_WKVBT);
  bf16_t* woT   = (bf16_t*)(ws + OFF_WOT);
  float*  qkva  = (float*)(ws + OFF_QKVA);
  bf16_t* qan   = (bf16_t*)(ws + OFF_QAN);
  bf16_t* ckvn  = (bf16_t*)(ws + OFF_CKVN);
  float*  cosT  = (float*)(ws + OFF_COS);
  float*  sinT  = (float*)(ws + OFF_SIN);
  bf16_t* qfull = (bf16_t*)(ws + OFF_QFULL);
  bf16_t* kfull = (bf16_t*)(ws + OFF_KFULL);
  bf16_t* vt    = (bf16_t*)(ws + OFF_VT);
  bf16_t* attn  = (bf16_t*)(ws + OFF_ATTN);

  // conversions / tables
  k_cvt_bf16<<<2048, 256, 0, stream>>>(x, xb, 2048 * 2048);
  k_transpose_cvt<<<dim3(768 / 32, 2048 / 32), 256, 0, stream>>>(w_qa, wat, 2048, 768, 768);
  k_transpose_cvt<<<dim3(640 / 32, 2048 / 32), 256, 0, stream>>>(w_kva, wat + (size_t)768 * 2048, 2048, 576, 640);
  k_transpose_cvt<<<dim3(3072 / 32, 768 / 32), 256, 0, stream>>>(w_qb, wqbT, 768, 3072, 3072);
  k_transpose_cvt<<<dim3(4096 / 32, 512 / 32), 256, 0, stream>>>(w_kvb, wkvbT, 512, 4096, 4096);
  k_transpose_cvt<<<dim3(2048 / 32, 2048 / 32), 256, 0, stream>>>(w_o, woT, 2048, 2048, 2048);
  k_rope_tables<<<2048 * 64 / 256, 256, 0, stream>>>(cosT, sinT);

  // qkv_a = x @ [w_qa | w_kva]   (fp32 out, N=1408)
  k_gemm<0><<<dim3(1408 / 128, 16), 256, 0, stream>>>(xb, wat, 2048, 1408, 2048,
                                                      qkva, nullptr, nullptr, nullptr, nullptr);
  k_rmsnorm_q<<<2048, 256, 0, stream>>>(qkva, qnw, qan);
  k_rmsnorm_kv<<<2048, 256, 0, stream>>>(qkva, kvnw, ckvn, kfull, cosT, sinT);

  // q = qan @ w_qb, fused RoPE -> qfull
  k_gemm<1><<<dim3(3072 / 128, 16), 256, 0, stream>>>(qan, wqbT, 2048, 3072, 768,
                                                      nullptr, qfull, nullptr, cosT, sinT);
  // kv_up = ckvn @ w_kvb -> kfull nope part + vT
  k_gemm<2><<<dim3(4096 / 128, 16), 256, 0, stream>>>(ckvn, wkvbT, 2048, 4096, 512,
                                                      nullptr, kfull, vt, nullptr, nullptr);
  // attention
  k_attn<<<dim3(32, 16), 256, 0, stream>>>(qfull, kfull, vt, attn);
  // out = attn @ w_o
  k_gemm<0><<<dim3(2048 / 128, 16), 256, 0, stream>>>(attn, woT, 2048, 2048, 2048,
                                                      out, nullptr, nullptr, nullptr, nullptr);
}

// Round 4
// 380.406 us; speedup vs baseline: 1.6194x; 1.6194x over previous
//
#include <hip/hip_runtime.h>
#include <hip/hip_bf16.h>
#include <stdint.h>

typedef __bf16 bf16_t;
typedef bf16_t bf16x8 __attribute__((ext_vector_type(8)));
typedef bf16_t bf16x4 __attribute__((ext_vector_type(4)));
typedef float  f32x4  __attribute__((ext_vector_type(4)));

#define SLEN 2048
#define NHEAD 16

// ---------------- workspace layout (bytes) ----------------
static const size_t OFF_XB    = 0;          // x bf16            (2048*2048*2 = 8388608)
static const size_t OFF_WAT   = 8388608;    // [w_qa|w_kva]^T    (1408*2048*2 = 5767168)
static const size_t OFF_WQBT  = 14155776;   // w_qb^T            (3072*768*2  = 4718592)
static const size_t OFF_WKVBT = 18874368;   // w_kvb^T           (4096*512*2  = 4194304)
static const size_t OFF_WOT   = 23068672;   // w_o^T             (2048*2048*2 = 8388608)
static const size_t OFF_QKVA  = 31457280;   // qkv_a fp32        (2048*1408*4 = 11534336)
static const size_t OFF_QAN   = 42991616;   // q_a normed bf16   (2048*768*2  = 3145728)
static const size_t OFF_CKVN  = 46137344;   // c_kv normed bf16  (2048*512*2  = 2097152)
static const size_t OFF_COS   = 48234496;   // cos table f32     (2048*64*4   = 524288)
static const size_t OFF_SIN   = 48758784;   // sin table f32     (524288)
static const size_t OFF_QFULL = 49283072;   // q_full bf16 (H,S,192) (12582912)
static const size_t OFF_KFULL = 61865984;   // k_full bf16 (H,S,192) (12582912)
static const size_t OFF_VT    = 74448896;   // v^T bf16 (H,128,S)    (8388608)
static const size_t OFF_ATTN  = 82837504;   // attn out bf16 (S,2048)(8388608)
// total 91,226,112 B

__device__ __forceinline__ void gll16(const void* g, void* l) {
  __builtin_amdgcn_global_load_lds((__attribute__((address_space(1))) void*)g,
                                   (__attribute__((address_space(3))) void*)l,
                                   16, 0, 0);
}

// ---------------- fp32 -> bf16 elementwise ----------------
__global__ __launch_bounds__(256) void k_cvt_bf16(const float* __restrict__ in,
                                                  bf16_t* __restrict__ out, int n) {
  int i = (blockIdx.x * 256 + threadIdx.x) * 8;
  if (i >= n) return;
  f32x4 a = *(const f32x4*)&in[i];
  f32x4 b = *(const f32x4*)&in[i + 4];
  bf16x8 o;
  #pragma unroll
  for (int j = 0; j < 4; j++) { o[j] = (bf16_t)a[j]; o[j + 4] = (bf16_t)b[j]; }
  *(bf16x8*)&out[i] = o;
}

// ---------------- transpose + convert: w(K,N) f32 -> wT(Nout,K) bf16, rows>=N zero ----------------
__global__ __launch_bounds__(256) void k_transpose_cvt(const float* __restrict__ in,
                                                       bf16_t* __restrict__ out,
                                                       int K, int N, int Nout) {
  __shared__ float tile[32][33];
  const int nt = blockIdx.x, kt = blockIdx.y;
  const int t = threadIdx.x;
  const int r = t >> 3, c4 = (t & 7) * 4;
  const int gk = kt * 32 + r;
  #pragma unroll
  for (int j = 0; j < 4; j++) {
    int gn = nt * 32 + c4 + j;
    tile[r][c4 + j] = (gn < N) ? in[(size_t)gk * N + gn] : 0.f;
  }
  __syncthreads();
  bf16x4 o;
  #pragma unroll
  for (int j = 0; j < 4; j++) o[j] = (bf16_t)tile[c4 + j][r];
  *(bf16x4*)&out[(size_t)(nt * 32 + r) * K + kt * 32 + c4] = o;
}

// ---------------- rope tables: cos/sin (S,64) f32 ----------------
__global__ __launch_bounds__(256) void k_rope_tables(float* __restrict__ cosT,
                                                     float* __restrict__ sinT) {
  int i = blockIdx.x * 256 + threadIdx.x;          // S*64 total
  int s = i >> 6, d = i & 63;
  float invf = powf(10000.f, -(float)(2 * (d & 31)) / 64.f);
  float ang = (float)s * invf;
  cosT[i] = cosf(ang);
  sinT[i] = sinf(ang);
}

// ---------------- generic 128x128 bf16 MFMA GEMM, B^T input ----------------
template<int EPI>
__global__ __launch_bounds__(256) void k_gemm(const bf16_t* __restrict__ A,
                                              const bf16_t* __restrict__ Bt,
                                              int M, int N, int K,
                                              float* __restrict__ Cf,
                                              bf16_t* __restrict__ O1,
                                              bf16_t* __restrict__ O2,
                                              const float* __restrict__ cosT,
                                              const float* __restrict__ sinT) {
  __shared__ __align__(16) bf16_t sA[128 * 32];
  __shared__ __align__(16) bf16_t sB[128 * 32];
  const int t = threadIdx.x;
  const int lane = t & 63, wave = t >> 6;
  const int l15 = lane & 15, l4 = lane >> 4;
  const int wr = wave >> 1, wc = wave & 1;
  const int rowBase = blockIdx.y * 128, colBase = blockIdx.x * 128;

  f32x4 acc[4][4] = {};

  const int c0 = t, c1 = t + 256;
  const size_t aoff0 = (size_t)(rowBase + (c0 >> 2)) * K + (c0 & 3) * 8;
  const size_t aoff1 = (size_t)(rowBase + (c1 >> 2)) * K + (c1 & 3) * 8;
  const size_t boff0 = (size_t)(colBase + (c0 >> 2)) * K + (c0 & 3) * 8;
  const size_t boff1 = (size_t)(colBase + (c1 >> 2)) * K + (c1 & 3) * 8;

  for (int k0 = 0; k0 < K; k0 += 32) {
    gll16(A + aoff0 + k0, sA + wave * 512);
    gll16(A + aoff1 + k0, sA + 2048 + wave * 512);
    gll16(Bt + boff0 + k0, sB + wave * 512);
    gll16(Bt + boff1 + k0, sB + 2048 + wave * 512);
    __syncthreads();
    bf16x8 af[4], bfv[4];
    #pragma unroll
    for (int m = 0; m < 4; m++)
      af[m] = *(const bf16x8*)&sA[(wr * 64 + m * 16 + l15) * 32 + l4 * 8];
    #pragma unroll
    for (int n = 0; n < 4; n++)
      bfv[n] = *(const bf16x8*)&sB[(wc * 64 + n * 16 + l15) * 32 + l4 * 8];
    #pragma unroll
    for (int m = 0; m < 4; m++)
      #pragma unroll
      for (int n = 0; n < 4; n++)
        acc[m][n] = __builtin_amdgcn_mfma_f32_16x16x32_bf16(af[m], bfv[n], acc[m][n], 0, 0, 0);
    __syncthreads();
  }

  if (EPI == 0) {
    #pragma unroll
    for (int m = 0; m < 4; m++)
      #pragma unroll
      for (int n = 0; n < 4; n++)
        #pragma unroll
        for (int r = 0; r < 4; r++) {
          int row = rowBase + wr * 64 + m * 16 + l4 * 4 + r;
          int col = colBase + wc * 64 + n * 16 + l15;
          Cf[(size_t)row * N + col] = acc[m][n][r];
        }
  } else if (EPI == 1) {
    #pragma unroll
    for (int m = 0; m < 4; m++)
      #pragma unroll
      for (int n = 0; n < 4; n++) {
        int cb = colBase + wc * 64 + n * 16 + l15;
        int h = cb / 192, d = cb - h * 192;
        #pragma unroll
        for (int r = 0; r < 4; r++) {
          int s = rowBase + wr * 64 + m * 16 + l4 * 4 + r;
          float v = acc[m][n][r];
          float p = __shfl_xor(v, 1);   // pair partner (cols are lane-consecutive)
          float o = v;
          if (d >= 128) {
            int i = d - 128;
            float cs = cosT[s * 64 + i], sn = sinT[s * 64 + i];
            o = (i & 1) ? (v * cs + p * sn) : (v * cs - p * sn);
          }
          O1[((size_t)h * SLEN + s) * 192 + d] = (bf16_t)o;
        }
      }
  } else { // EPI == 2
    #pragma unroll
    for (int m = 0; m < 4; m++)
      #pragma unroll
      for (int n = 0; n < 4; n++) {
        int cb = colBase + wc * 64 + n * 16 + l15;
        int h = cb >> 8, w = cb & 255;
        if (w < 128) {
          #pragma unroll
          for (int r = 0; r < 4; r++) {
            int s = rowBase + wr * 64 + m * 16 + l4 * 4 + r;
            O1[((size_t)h * SLEN + s) * 192 + w] = (bf16_t)acc[m][n][r];
          }
        } else {
          int d = w - 128;
          int s0 = rowBase + wr * 64 + m * 16 + l4 * 4;
          bf16x4 o;
          #pragma unroll
          for (int r = 0; r < 4; r++) o[r] = (bf16_t)acc[m][n][r];
          *(bf16x4*)&O2[((size_t)h * 128 + d) * SLEN + s0] = o;
        }
      }
  }
}

// ---------------- RMSNorm q_a rows (768) -> bf16 ----------------
__global__ __launch_bounds__(256) void k_rmsnorm_q(const float* __restrict__ qkv,
                                                   const float* __restrict__ w,
                                                   bf16_t* __restrict__ out) {
  __shared__ float red[4];
  const int row = blockIdx.x, t = threadIdx.x;
  const float* x = qkv + (size_t)row * 1408;
  float v0 = x[t], v1 = x[t + 256], v2 = x[t + 512];
  float ss = v0 * v0 + v1 * v1 + v2 * v2;
  #pragma unroll
  for (int off = 32; off; off >>= 1) ss += __shfl_down(ss, off);
  if ((t & 63) == 0) red[t >> 6] = ss;
  __syncthreads();
  ss = red[0] + red[1] + red[2] + red[3];
  float rs = rsqrtf(ss * (1.f / 768.f) + 1e-6f);
  out[(size_t)row * 768 + t]       = (bf16_t)(v0 * rs * w[t]);
  out[(size_t)row * 768 + t + 256] = (bf16_t)(v1 * rs * w[t + 256]);
  out[(size_t)row * 768 + t + 512] = (bf16_t)(v2 * rs * w[t + 512]);
}

// ---------------- RMSNorm c_kv rows (512) + k_rope RoPE broadcast ----------------
__global__ __launch_bounds__(256) void k_rmsnorm_kv(const float* __restrict__ qkv,
                                                    const float* __restrict__ w,
                                                    bf16_t* __restrict__ ckvn,
                                                    bf16_t* __restrict__ kfull,
                                                    const float* __restrict__ cosT,
                                                    const float* __restrict__ sinT) {
  __shared__ float red[4];
  const int row = blockIdx.x, t = threadIdx.x;
  const float* x = qkv + (size_t)row * 1408 + 768;
  float v0 = x[t], v1 = x[t + 256];
  float ss = v0 * v0 + v1 * v1;
  #pragma unroll
  for (int off = 32; off; off >>= 1) ss += __shfl_down(ss, off);
  if ((t & 63) == 0) red[t >> 6] = ss;
  __syncthreads();
  ss = red[0] + red[1] + red[2] + red[3];
  float rs = rsqrtf(ss * (1.f / 512.f) + 1e-6f);
  ckvn[(size_t)row * 512 + t]       = (bf16_t)(v0 * rs * w[t]);
  ckvn[(size_t)row * 512 + t + 256] = (bf16_t)(v1 * rs * w[t + 256]);
  if (t < 64) {
    float xv = x[512 + t];
    float xo = x[512 + (t ^ 1)];
    float cs = cosT[row * 64 + t], sn = sinT[row * 64 + t];
    float o = (t & 1) ? (xv * cs + xo * sn) : (xv * cs - xo * sn);
    bf16_t ob = (bf16_t)o;
    for (int h = 0; h < NHEAD; h++)
      kfull[((size_t)h * SLEN + row) * 192 + 128 + t] = ob;
  }
}

// ---------------- causal flash attention, LDS-staged K/V ----------------
// grid (32 qblocks heavy-first, 16 heads), 256 threads = 4 waves sharing the
// 64-row q-block and the staged K/V tiles. K double-buffered, V single.
// LDS tiles XOR-swizzled (byte ^= ((row&7)<<4)); gll16 dest is linear, so the
// swizzle is applied on the per-lane GLOBAL source offset (involution) and on
// the ds_read address (rule 21: both-sides-or-neither).
__global__ __launch_bounds__(256) void k_attn(const bf16_t* __restrict__ qfull,
                                              const bf16_t* __restrict__ kfull,
                                              const bf16_t* __restrict__ vT,
                                              bf16_t* __restrict__ out) {
  __shared__ __align__(16) bf16_t sK[2][64 * 192];  // 49152 B
  __shared__ __align__(16) bf16_t sV[128 * 64];     // 16384 B  [d][kv]
  __shared__ __align__(16) bf16_t P[4][16][72];     // 9216 B per-wave P tiles
  const int qb = 31 - blockIdx.x, h = blockIdx.y;   // heavy blocks first
  const int t = threadIdx.x, lane = t & 63, wave = t >> 6;
  const int l15 = lane & 15, l4 = lane >> 4;
  const int qr0 = qb * 64 + wave * 16;
  const bf16_t* qh = qfull + (size_t)h * SLEN * 192;
  const bf16_t* kh = kfull + (size_t)h * SLEN * 192;
  const bf16_t* vh = vT + (size_t)h * 128 * SLEN;

  // per-lane swizzled staging source offsets (elements within tile)
  int koff[6];
  #pragma unroll
  for (int i = 0; i < 6; i++) {
    int D = wave * 6144 + i * 1024 + lane * 16;   // linear LDS byte dest
    int row = D / 384, cb = D - row * 384;
    koff[i] = row * 192 + ((cb ^ ((row & 7) << 4)) >> 1);
  }
  int voff[4];
  #pragma unroll
  for (int i = 0; i < 4; i++) {
    int D = wave * 4096 + i * 1024 + lane * 16;
    int row = D >> 7, cb = D & 127;
    voff[i] = row * SLEN + ((cb ^ ((row & 7) << 4)) >> 1);
  }
  const int sswz = (l15 & 7) << 4;   // read-side swizzle (row&7 == l15&7)

  bf16x8 qf[6];
  #pragma unroll
  for (int kk = 0; kk < 6; kk++)
    qf[kk] = *(const bf16x8*)&qh[(size_t)(qr0 + l15) * 192 + kk * 32 + l4 * 8];

  f32x4 oacc[8] = {};
  float mrun[4], lrun[4];
  #pragma unroll
  for (int r = 0; r < 4; r++) { mrun[r] = -3e30f; lrun[r] = 0.f; }
  const float scale = 0.0721687836f;  // 1/sqrt(192)
  int rowq[4];
  #pragma unroll
  for (int r = 0; r < 4; r++) rowq[r] = qr0 + l4 * 4 + r;

  // prologue: stage K[0], V for kb=0
  #pragma unroll
  for (int i = 0; i < 6; i++)
    gll16(kh + koff[i], (char*)&sK[0][0] + wave * 6144 + i * 1024);
  #pragma unroll
  for (int i = 0; i < 4; i++)
    gll16(vh + voff[i], (char*)&sV[0] + wave * 4096 + i * 1024);
  __syncthreads();

  int cur = 0;
  for (int kb = 0; kb <= qb; kb++) {
    const int kv0 = kb * 64;
    // ---- QK^T from sK[cur]
    f32x4 sc[4] = {};
    #pragma unroll
    for (int kk = 0; kk < 6; kk++)
      #pragma unroll
      for (int n = 0; n < 4; n++) {
        const bf16_t* p = (const bf16_t*)((const char*)&sK[cur][0] +
                            (n * 16 + l15) * 384 + ((kk * 64 + l4 * 16) ^ sswz));
        bf16x8 bv = *(const bf16x8*)p;
        sc[n] = __builtin_amdgcn_mfma_f32_16x16x32_bf16(qf[kk], bv, sc[n], 0, 0, 0);
      }
    // ---- prefetch next K tile into the other buffer (covered by softmax+PV)
    if (kb < qb) {
      const bf16_t* ksrc = kh + (size_t)(kv0 + 64) * 192;
      #pragma unroll
      for (int i = 0; i < 6; i++)
        gll16(ksrc + koff[i], (char*)&sK[cur ^ 1][0] + wave * 6144 + i * 1024);
    }
    // ---- softmax (per-wave, 16 q rows)
    float sv[4][4];
    const bool diag = (kb == qb);
    #pragma unroll
    for (int n = 0; n < 4; n++)
      #pragma unroll
      for (int r = 0; r < 4; r++) {
        float v = sc[n][r] * scale;
        if (diag && (kv0 + n * 16 + l15 > rowq[r])) v = -3e30f;
        sv[n][r] = v;
      }
    float fac[4];
    #pragma unroll
    for (int r = 0; r < 4; r++) {
      float rm = fmaxf(fmaxf(sv[0][r], sv[1][r]), fmaxf(sv[2][r], sv[3][r]));
      #pragma unroll
      for (int off = 1; off < 16; off <<= 1) rm = fmaxf(rm, __shfl_xor(rm, off));
      float mn = fmaxf(mrun[r], rm);
      fac[r] = __expf(mrun[r] - mn);
      mrun[r] = mn;
    }
    float psum[4] = {0.f, 0.f, 0.f, 0.f};
    #pragma unroll
    for (int n = 0; n < 4; n++)
      #pragma unroll
      for (int r = 0; r < 4; r++) {
        float p = __expf(sv[n][r] - mrun[r]);
        psum[r] += p;
        P[wave][l4 * 4 + r][n * 16 + l15] = (bf16_t)p;
      }
    #pragma unroll
    for (int r = 0; r < 4; r++) {
      #pragma unroll
      for (int off = 1; off < 16; off <<= 1) psum[r] += __shfl_xor(psum[r], off);
      lrun[r] = lrun[r] * fac[r] + psum[r];
    }
    #pragma unroll
    for (int n8 = 0; n8 < 8; n8++)
      #pragma unroll
      for (int r = 0; r < 4; r++) oacc[n8][r] *= fac[r];
    // ---- PV from sV (B-frag: col=d, k=kv)
    #pragma unroll
    for (int kk = 0; kk < 2; kk++) {
      bf16x8 pa = *(const bf16x8*)&P[wave][l15][kk * 32 + l4 * 8];
      #pragma unroll
      for (int n8 = 0; n8 < 8; n8++) {
        const bf16_t* p = (const bf16_t*)((const char*)&sV[0] +
                            (n8 * 16 + l15) * 128 + ((kk * 64 + l4 * 16) ^ sswz));
        bf16x8 vb = *(const bf16x8*)p;
        oacc[n8] = __builtin_amdgcn_mfma_f32_16x16x32_bf16(pa, vb, oacc[n8], 0, 0, 0);
      }
    }
    __syncthreads();          // all waves done reading sV (and sK[cur])
    if (kb < qb) {
      const bf16_t* vsrc = vh + kv0 + 64;
      #pragma unroll
      for (int i = 0; i < 4; i++)
        gll16(vsrc + voff[i], (char*)&sV[0] + wave * 4096 + i * 1024);
    }
    __syncthreads();          // V staged (barrier drains vmcnt)
    cur ^= 1;
  }

  #pragma unroll
  for (int n8 = 0; n8 < 8; n8++)
    #pragma unroll
    for (int r = 0; r < 4; r++) {
      int s = qr0 + l4 * 4 + r;
      out[(size_t)s * 2048 + h * 128 + n8 * 16 + l15] = (bf16_t)(oacc[n8][r] / lrun[r]);
    }
}

// ---------------- launcher ----------------
extern "C" void kernel_launch(void* const* d_in, const int* in_sizes, int n_in,
                              void* d_out, int out_size, void* d_ws, size_t ws_size,
                              hipStream_t stream) {
  const float* x     = (const float*)d_in[0];
  const float* w_qa  = (const float*)d_in[1];
  const float* qnw   = (const float*)d_in[2];
  const float* w_qb  = (const float*)d_in[3];
  const float* w_kva = (const float*)d_in[4];
  const float* kvnw  = (const float*)d_in[5];
  const float* w_kvb = (const float*)d_in[6];
  const float* w_o   = (const float*)d_in[7];
  float* out = (float*)d_out;
  char* ws = (char*)d_ws;

  bf16_t* xb    = (bf16_t*)(ws + OFF_XB);
  bf16_t* wat   = (bf16_t*)(ws + OFF_WAT);
  bf16_t* wqbT  = (bf16_t*)(ws + OFF_WQBT);
  bf16_t* wkvbT = (bf16_t*)(ws + OFF_WKVBT);
  bf16_t* woT   = (bf16_t*)(ws + OFF_WOT);
  float*  qkva  = (float*)(ws + OFF_QKVA);
  bf16_t* qan   = (bf16_t*)(ws + OFF_QAN);
  bf16_t* ckvn  = (bf16_t*)(ws + OFF_CKVN);
  float*  cosT  = (float*)(ws + OFF_COS);
  float*  sinT  = (float*)(ws + OFF_SIN);
  bf16_t* qfull = (bf16_t*)(ws + OFF_QFULL);
  bf16_t* kfull = (bf16_t*)(ws + OFF_KFULL);
  bf16_t* vt    = (bf16_t*)(ws + OFF_VT);
  bf16_t* attn  = (bf16_t*)(ws + OFF_ATTN);

  // conversions / tables
  k_cvt_bf16<<<2048, 256, 0, stream>>>(x, xb, 2048 * 2048);
  k_transpose_cvt<<<dim3(768 / 32, 2048 / 32), 256, 0, stream>>>(w_qa, wat, 2048, 768, 768);
  k_transpose_cvt<<<dim3(640 / 32, 2048 / 32), 256, 0, stream>>>(w_kva, wat + (size_t)768 * 2048, 2048, 576, 640);
  k_transpose_cvt<<<dim3(3072 / 32, 768 / 32), 256, 0, stream>>>(w_qb, wqbT, 768, 3072, 3072);
  k_transpose_cvt<<<dim3(4096 / 32, 512 / 32), 256, 0, stream>>>(w_kvb, wkvbT, 512, 4096, 4096);
  k_transpose_cvt<<<dim3(2048 / 32, 2048 / 32), 256, 0, stream>>>(w_o, woT, 2048, 2048, 2048);
  k_rope_tables<<<2048 * 64 / 256, 256, 0, stream>>>(cosT, sinT);

  // qkv_a = x @ [w_qa | w_kva]   (fp32 out, N=1408)
  k_gemm<0><<<dim3(1408 / 128, 16), 256, 0, stream>>>(xb, wat, 2048, 1408, 2048,
                                                      qkva, nullptr, nullptr, nullptr, nullptr);
  k_rmsnorm_q<<<2048, 256, 0, stream>>>(qkva, qnw, qan);
  k_rmsnorm_kv<<<2048, 256, 0, stream>>>(qkva, kvnw, ckvn, kfull, cosT, sinT);

  // q = qan @ w_qb, fused RoPE -> qfull
  k_gemm<1><<<dim3(3072 / 128, 16), 256, 0, stream>>>(qan, wqbT, 2048, 3072, 768,
                                                      nullptr, qfull, nullptr, cosT, sinT);
  // kv_up = ckvn @ w_kvb -> kfull nope part + vT
  k_gemm<2><<<dim3(4096 / 128, 16), 256, 0, stream>>>(ckvn, wkvbT, 2048, 4096, 512,
                                                      nullptr, kfull, vt, nullptr, nullptr);
  // attention
  k_attn<<<dim3(32, 16), 256, 0, stream>>>(qfull, kfull, vt, attn);
  // out = attn @ w_o
  k_gemm<0><<<dim3(2048 / 128, 16), 256, 0, stream>>>(attn, woT, 2048, 2048, 2048,
                                                      out, nullptr, nullptr, nullptr, nullptr);
}

// Round 9
// 371.341 us; speedup vs baseline: 1.6590x; 1.0244x over previous
//
#include <hip/hip_runtime.h>
#include <hip/hip_bf16.h>
#include <stdint.h>

typedef __bf16 bf16_t;
typedef bf16_t bf16x8 __attribute__((ext_vector_type(8)));
typedef bf16_t bf16x4 __attribute__((ext_vector_type(4)));
typedef float  f32x4  __attribute__((ext_vector_type(4)));

#define SLEN 2048
#define NHEAD 16

// ---------------- workspace layout (bytes) ----------------
static const size_t OFF_XB    = 0;          // x bf16            (2048*2048*2 = 8388608)
static const size_t OFF_WAT   = 8388608;    // [w_qa|w_kva]^T    (1408*2048*2 = 5767168)
static const size_t OFF_WQBT  = 14155776;   // w_qb^T            (3072*768*2  = 4718592)
static const size_t OFF_WKVBT = 18874368;   // w_kvb^T           (4096*512*2  = 4194304)
static const size_t OFF_WOT   = 23068672;   // w_o^T             (2048*2048*2 = 8388608)
static const size_t OFF_QKVA  = 31457280;   // qkv_a fp32        (2048*1408*4 = 11534336)
static const size_t OFF_QAN   = 42991616;   // q_a normed bf16   (2048*768*2  = 3145728)
static const size_t OFF_CKVN  = 46137344;   // c_kv normed bf16  (2048*512*2  = 2097152)
static const size_t OFF_COS   = 48234496;   // cos table f32     (2048*64*4   = 524288)
static const size_t OFF_SIN   = 48758784;   // sin table f32     (524288)
static const size_t OFF_QFULL = 49283072;   // q_full bf16 (H,S,192) (12582912)
static const size_t OFF_KFULL = 61865984;   // k_full bf16 (H,S,192) (12582912)
static const size_t OFF_VT    = 74448896;   // v^T bf16 (H,128,S)    (8388608)
static const size_t OFF_ATTN  = 82837504;   // attn out bf16 (S,2048)(8388608)
// total 91,226,112 B

__device__ __forceinline__ void gll16(const void* g, void* l) {
  __builtin_amdgcn_global_load_lds((__attribute__((address_space(1))) void*)g,
                                   (__attribute__((address_space(3))) void*)l,
                                   16, 0, 0);
}

// ---------------- fp32 -> bf16 elementwise ----------------
__global__ __launch_bounds__(256) void k_cvt_bf16(const float* __restrict__ in,
                                                  bf16_t* __restrict__ out, int n) {
  int i = (blockIdx.x * 256 + threadIdx.x) * 8;
  if (i >= n) return;
  f32x4 a = *(const f32x4*)&in[i];
  f32x4 b = *(const f32x4*)&in[i + 4];
  bf16x8 o;
  #pragma unroll
  for (int j = 0; j < 4; j++) { o[j] = (bf16_t)a[j]; o[j + 4] = (bf16_t)b[j]; }
  *(bf16x8*)&out[i] = o;
}

// ---------------- transpose + convert: w(K,N) f32 -> wT(Nout,K) bf16, rows>=N zero ----------------
__global__ __launch_bounds__(256) void k_transpose_cvt(const float* __restrict__ in,
                                                       bf16_t* __restrict__ out,
                                                       int K, int N, int Nout) {
  __shared__ float tile[32][33];
  const int nt = blockIdx.x, kt = blockIdx.y;
  const int t = threadIdx.x;
  const int r = t >> 3, c4 = (t & 7) * 4;
  const int gk = kt * 32 + r;
  #pragma unroll
  for (int j = 0; j < 4; j++) {
    int gn = nt * 32 + c4 + j;
    tile[r][c4 + j] = (gn < N) ? in[(size_t)gk * N + gn] : 0.f;
  }
  __syncthreads();
  bf16x4 o;
  #pragma unroll
  for (int j = 0; j < 4; j++) o[j] = (bf16_t)tile[c4 + j][r];
  *(bf16x4*)&out[(size_t)(nt * 32 + r) * K + kt * 32 + c4] = o;
}

// ---------------- rope tables: cos/sin (S,64) f32 ----------------
__global__ __launch_bounds__(256) void k_rope_tables(float* __restrict__ cosT,
                                                     float* __restrict__ sinT) {
  int i = blockIdx.x * 256 + threadIdx.x;          // S*64 total
  int s = i >> 6, d = i & 63;
  float invf = powf(10000.f, -(float)(2 * (d & 31)) / 64.f);
  float ang = (float)s * invf;
  cosT[i] = cosf(ang);
  sinT[i] = sinf(ang);
}

// ---------------- generic 128x128 bf16 MFMA GEMM, B^T input ----------------
template<int EPI>
__global__ __launch_bounds__(256) void k_gemm(const bf16_t* __restrict__ A,
                                              const bf16_t* __restrict__ Bt,
                                              int M, int N, int K,
                                              float* __restrict__ Cf,
                                              bf16_t* __restrict__ O1,
                                              bf16_t* __restrict__ O2,
                                              const float* __restrict__ cosT,
                                              const float* __restrict__ sinT) {
  __shared__ __align__(16) bf16_t sA[128 * 32];
  __shared__ __align__(16) bf16_t sB[128 * 32];
  const int t = threadIdx.x;
  const int lane = t & 63, wave = t >> 6;
  const int l15 = lane & 15, l4 = lane >> 4;
  const int wr = wave >> 1, wc = wave & 1;
  const int rowBase = blockIdx.y * 128, colBase = blockIdx.x * 128;

  f32x4 acc[4][4] = {};

  const int c0 = t, c1 = t + 256;
  const size_t aoff0 = (size_t)(rowBase + (c0 >> 2)) * K + (c0 & 3) * 8;
  const size_t aoff1 = (size_t)(rowBase + (c1 >> 2)) * K + (c1 & 3) * 8;
  const size_t boff0 = (size_t)(colBase + (c0 >> 2)) * K + (c0 & 3) * 8;
  const size_t boff1 = (size_t)(colBase + (c1 >> 2)) * K + (c1 & 3) * 8;

  for (int k0 = 0; k0 < K; k0 += 32) {
    gll16(A + aoff0 + k0, sA + wave * 512);
    gll16(A + aoff1 + k0, sA + 2048 + wave * 512);
    gll16(Bt + boff0 + k0, sB + wave * 512);
    gll16(Bt + boff1 + k0, sB + 2048 + wave * 512);
    __syncthreads();
    bf16x8 af[4], bfv[4];
    #pragma unroll
    for (int m = 0; m < 4; m++)
      af[m] = *(const bf16x8*)&sA[(wr * 64 + m * 16 + l15) * 32 + l4 * 8];
    #pragma unroll
    for (int n = 0; n < 4; n++)
      bfv[n] = *(const bf16x8*)&sB[(wc * 64 + n * 16 + l15) * 32 + l4 * 8];
    #pragma unroll
    for (int m = 0; m < 4; m++)
      #pragma unroll
      for (int n = 0; n < 4; n++)
        acc[m][n] = __builtin_amdgcn_mfma_f32_16x16x32_bf16(af[m], bfv[n], acc[m][n], 0, 0, 0);
    __syncthreads();
  }

  if (EPI == 0) {
    #pragma unroll
    for (int m = 0; m < 4; m++)
      #pragma unroll
      for (int n = 0; n < 4; n++)
        #pragma unroll
        for (int r = 0; r < 4; r++) {
          int row = rowBase + wr * 64 + m * 16 + l4 * 4 + r;
          int col = colBase + wc * 64 + n * 16 + l15;
          Cf[(size_t)row * N + col] = acc[m][n][r];
        }
  } else if (EPI == 1) {
    #pragma unroll
    for (int m = 0; m < 4; m++)
      #pragma unroll
      for (int n = 0; n < 4; n++) {
        int cb = colBase + wc * 64 + n * 16 + l15;
        int h = cb / 192, d = cb - h * 192;
        #pragma unroll
        for (int r = 0; r < 4; r++) {
          int s = rowBase + wr * 64 + m * 16 + l4 * 4 + r;
          float v = acc[m][n][r];
          float p = __shfl_xor(v, 1);   // pair partner (cols are lane-consecutive)
          float o = v;
          if (d >= 128) {
            int i = d - 128;
            float cs = cosT[s * 64 + i], sn = sinT[s * 64 + i];
            o = (i & 1) ? (v * cs + p * sn) : (v * cs - p * sn);
          }
          O1[((size_t)h * SLEN + s) * 192 + d] = (bf16_t)o;
        }
      }
  } else { // EPI == 2
    #pragma unroll
    for (int m = 0; m < 4; m++)
      #pragma unroll
      for (int n = 0; n < 4; n++) {
        int cb = colBase + wc * 64 + n * 16 + l15;
        int h = cb >> 8, w = cb & 255;
        if (w < 128) {
          #pragma unroll
          for (int r = 0; r < 4; r++) {
            int s = rowBase + wr * 64 + m * 16 + l4 * 4 + r;
            O1[((size_t)h * SLEN + s) * 192 + w] = (bf16_t)acc[m][n][r];
          }
        } else {
          int d = w - 128;
          int s0 = rowBase + wr * 64 + m * 16 + l4 * 4;
          bf16x4 o;
          #pragma unroll
          for (int r = 0; r < 4; r++) o[r] = (bf16_t)acc[m][n][r];
          *(bf16x4*)&O2[((size_t)h * 128 + d) * SLEN + s0] = o;
        }
      }
  }
}

// ---------------- RMSNorm q_a rows (768) -> bf16 ----------------
__global__ __launch_bounds__(256) void k_rmsnorm_q(const float* __restrict__ qkv,
                                                   const float* __restrict__ w,
                                                   bf16_t* __restrict__ out) {
  __shared__ float red[4];
  const int row = blockIdx.x, t = threadIdx.x;
  const float* x = qkv + (size_t)row * 1408;
  float v0 = x[t], v1 = x[t + 256], v2 = x[t + 512];
  float ss = v0 * v0 + v1 * v1 + v2 * v2;
  #pragma unroll
  for (int off = 32; off; off >>= 1) ss += __shfl_down(ss, off);
  if ((t & 63) == 0) red[t >> 6] = ss;
  __syncthreads();
  ss = red[0] + red[1] + red[2] + red[3];
  float rs = rsqrtf(ss * (1.f / 768.f) + 1e-6f);
  out[(size_t)row * 768 + t]       = (bf16_t)(v0 * rs * w[t]);
  out[(size_t)row * 768 + t + 256] = (bf16_t)(v1 * rs * w[t + 256]);
  out[(size_t)row * 768 + t + 512] = (bf16_t)(v2 * rs * w[t + 512]);
}

// ---------------- RMSNorm c_kv rows (512) + k_rope RoPE broadcast ----------------
__global__ __launch_bounds__(256) void k_rmsnorm_kv(const float* __restrict__ qkv,
                                                    const float* __restrict__ w,
                                                    bf16_t* __restrict__ ckvn,
                                                    bf16_t* __restrict__ kfull,
                                                    const float* __restrict__ cosT,
                                                    const float* __restrict__ sinT) {
  __shared__ float red[4];
  const int row = blockIdx.x, t = threadIdx.x;
  const float* x = qkv + (size_t)row * 1408 + 768;
  float v0 = x[t], v1 = x[t + 256];
  float ss = v0 * v0 + v1 * v1;
  #pragma unroll
  for (int off = 32; off; off >>= 1) ss += __shfl_down(ss, off);
  if ((t & 63) == 0) red[t >> 6] = ss;
  __syncthreads();
  ss = red[0] + red[1] + red[2] + red[3];
  float rs = rsqrtf(ss * (1.f / 512.f) + 1e-6f);
  ckvn[(size_t)row * 512 + t]       = (bf16_t)(v0 * rs * w[t]);
  ckvn[(size_t)row * 512 + t + 256] = (bf16_t)(v1 * rs * w[t + 256]);
  if (t < 64) {
    float xv = x[512 + t];
    float xo = x[512 + (t ^ 1)];
    float cs = cosT[row * 64 + t], sn = sinT[row * 64 + t];
    float o = (t & 1) ? (xv * cs + xo * sn) : (xv * cs - xo * sn);
    bf16_t ob = (bf16_t)o;
    for (int h = 0; h < NHEAD; h++)
      kfull[((size_t)h * SLEN + row) * 192 + 128 + t] = ob;
  }
}

// ---------------- causal flash attention, pair-balanced + full double-buffer ----------------
// grid (16 qblock-pairs, 16 heads), 256 threads = 4 waves (16 q rows each).
// Block bx handles qb=bx then qb=31-bx -> exactly 33 KV-iterations per block
// (perfect balance; 256 blocks = 1/CU). K and V both double-buffered; next
// tile's global_load_lds issued at iteration top; ONE barrier per iteration
// drains it after ~a full iteration of compute cover (T3 2-phase pattern).
// LDS tiles XOR-swizzled (byte ^= ((row&7)<<4)); gll16 dest linear, swizzle
// applied on per-lane global source + ds_read address (rule 21).
__global__ __launch_bounds__(256) void k_attn(const bf16_t* __restrict__ qfull,
                                              const bf16_t* __restrict__ kfull,
                                              const bf16_t* __restrict__ vT,
                                              bf16_t* __restrict__ out) {
  __shared__ __align__(16) bf16_t sK[2][64 * 192];  // 2 x 24576 B
  __shared__ __align__(16) bf16_t sV[2][128 * 64];  // 2 x 16384 B  [d][kv]
  __shared__ __align__(16) bf16_t P[4][16][72];     // 9216 B per-wave P tiles
  const int bx = blockIdx.x, h = blockIdx.y;
  const int t = threadIdx.x, lane = t & 63, wave = t >> 6;
  const int l15 = lane & 15, l4 = lane >> 4;
  const bf16_t* qh = qfull + (size_t)h * SLEN * 192;
  const bf16_t* kh = kfull + (size_t)h * SLEN * 192;
  const bf16_t* vh = vT + (size_t)h * 128 * SLEN;

  // per-lane swizzled staging source offsets (elements within tile)
  int koff[6];
  #pragma unroll
  for (int i = 0; i < 6; i++) {
    int D = wave * 6144 + i * 1024 + lane * 16;   // linear LDS byte dest
    int row = D / 384, cb = D - row * 384;
    koff[i] = row * 192 + ((cb ^ ((row & 7) << 4)) >> 1);
  }
  int voff[4];
  #pragma unroll
  for (int i = 0; i < 4; i++) {
    int D = wave * 4096 + i * 1024 + lane * 16;
    int row = D >> 7, cb = D & 127;
    voff[i] = row * SLEN + ((cb ^ ((row & 7) << 4)) >> 1);
  }
  const int sswz = (l15 & 7) << 4;   // read-side swizzle (row&7 == l15&7)
  const float scale = 0.0721687836f; // 1/sqrt(192)

  #pragma unroll 1
  for (int ph = 0; ph < 2; ph++) {
    const int qb = ph ? (31 - bx) : bx;
    const int qr0 = qb * 64 + wave * 16;

    bf16x8 qf[6];
    #pragma unroll
    for (int kk = 0; kk < 6; kk++)
      qf[kk] = *(const bf16x8*)&qh[(size_t)(qr0 + l15) * 192 + kk * 32 + l4 * 8];

    f32x4 oacc[8] = {};
    float mrun[4], lrun[4];
    #pragma unroll
    for (int r = 0; r < 4; r++) { mrun[r] = -3e30f; lrun[r] = 0.f; }
    int rowq[4];
    #pragma unroll
    for (int r = 0; r < 4; r++) rowq[r] = qr0 + l4 * 4 + r;

    // prologue: stage K[0], V[0] into buf 0 (prior phase's reads all behind
    // its loop-end barrier)
    #pragma unroll
    for (int i = 0; i < 6; i++)
      gll16(kh + koff[i], (char*)&sK[0][0] + wave * 6144 + i * 1024);
    #pragma unroll
    for (int i = 0; i < 4; i++)
      gll16(vh + voff[i], (char*)&sV[0][0] + wave * 4096 + i * 1024);
    __syncthreads();

    int cur = 0;
    for (int kb = 0; kb <= qb; kb++) {
      const int kv0 = kb * 64;
      // ---- issue next tile's staging first (covered by this iter's compute)
      if (kb < qb) {
        const bf16_t* ksrc = kh + (size_t)(kv0 + 64) * 192;
        #pragma unroll
        for (int i = 0; i < 6; i++)
          gll16(ksrc + koff[i], (char*)&sK[cur ^ 1][0] + wave * 6144 + i * 1024);
        const bf16_t* vsrc = vh + kv0 + 64;
        #pragma unroll
        for (int i = 0; i < 4; i++)
          gll16(vsrc + voff[i], (char*)&sV[cur ^ 1][0] + wave * 4096 + i * 1024);
      }
      // ---- QK^T from sK[cur]
      f32x4 sc[4] = {};
      #pragma unroll
      for (int kk = 0; kk < 6; kk++)
        #pragma unroll
        for (int n = 0; n < 4; n++) {
          const bf16_t* p = (const bf16_t*)((const char*)&sK[cur][0] +
                              (n * 16 + l15) * 384 + ((kk * 64 + l4 * 16) ^ sswz));
          bf16x8 bv = *(const bf16x8*)p;
          sc[n] = __builtin_amdgcn_mfma_f32_16x16x32_bf16(qf[kk], bv, sc[n], 0, 0, 0);
        }
      // ---- softmax (per-wave, 16 q rows)
      float sv[4][4];
      const bool diag = (kb == qb);
      #pragma unroll
      for (int n = 0; n < 4; n++)
        #pragma unroll
        for (int r = 0; r < 4; r++) {
          float v = sc[n][r] * scale;
          if (diag && (kv0 + n * 16 + l15 > rowq[r])) v = -3e30f;
          sv[n][r] = v;
        }
      float fac[4];
      #pragma unroll
      for (int r = 0; r < 4; r++) {
        float rm = fmaxf(fmaxf(sv[0][r], sv[1][r]), fmaxf(sv[2][r], sv[3][r]));
        #pragma unroll
        for (int off = 1; off < 16; off <<= 1) rm = fmaxf(rm, __shfl_xor(rm, off));
        float mn = fmaxf(mrun[r], rm);
        fac[r] = __expf(mrun[r] - mn);
        mrun[r] = mn;
      }
      float psum[4] = {0.f, 0.f, 0.f, 0.f};
      #pragma unroll
      for (int n = 0; n < 4; n++)
        #pragma unroll
        for (int r = 0; r < 4; r++) {
          float p = __expf(sv[n][r] - mrun[r]);
          psum[r] += p;
          P[wave][l4 * 4 + r][n * 16 + l15] = (bf16_t)p;
        }
      #pragma unroll
      for (int r = 0; r < 4; r++) {
        #pragma unroll
        for (int off = 1; off < 16; off <<= 1) psum[r] += __shfl_xor(psum[r], off);
        lrun[r] = lrun[r] * fac[r] + psum[r];
      }
      #pragma unroll
      for (int n8 = 0; n8 < 8; n8++)
        #pragma unroll
        for (int r = 0; r < 4; r++) oacc[n8][r] *= fac[r];
      // ---- PV from sV[cur] (B-frag: col=d, k=kv)
      #pragma unroll
      for (int kk = 0; kk < 2; kk++) {
        bf16x8 pa = *(const bf16x8*)&P[wave][l15][kk * 32 + l4 * 8];
        #pragma unroll
        for (int n8 = 0; n8 < 8; n8++) {
          const bf16_t* p = (const bf16_t*)((const char*)&sV[cur][0] +
                              (n8 * 16 + l15) * 128 + ((kk * 64 + l4 * 16) ^ sswz));
          bf16x8 vb = *(const bf16x8*)p;
          oacc[n8] = __builtin_amdgcn_mfma_f32_16x16x32_bf16(pa, vb, oacc[n8], 0, 0, 0);
        }
      }
      // ---- single barrier: drains prefetch (issued one full iter ago) and
      // guarantees all waves are done reading buf[cur] before it's re-staged
      __syncthreads();
      cur ^= 1;
    }

    #pragma unroll
    for (int n8 = 0; n8 < 8; n8++)
      #pragma unroll
      for (int r = 0; r < 4; r++) {
        int s = qr0 + l4 * 4 + r;
        out[(size_t)s * 2048 + h * 128 + n8 * 16 + l15] = (bf16_t)(oacc[n8][r] / lrun[r]);
      }
  }
}

// ---------------- launcher ----------------
extern "C" void kernel_launch(void* const* d_in, const int* in_sizes, int n_in,
                              void* d_out, int out_size, void* d_ws, size_t ws_size,
                              hipStream_t stream) {
  const float* x     = (const float*)d_in[0];
  const float* w_qa  = (const float*)d_in[1];
  const float* qnw   = (const float*)d_in[2];
  const float* w_qb  = (const float*)d_in[3];
  const float* w_kva = (const float*)d_in[4];
  const float* kvnw  = (const float*)d_in[5];
  const float* w_kvb = (const float*)d_in[6];
  const float* w_o   = (const float*)d_in[7];
  float* out = (float*)d_out;
  char* ws = (char*)d_ws;

  bf16_t* xb    = (bf16_t*)(ws + OFF_XB);
  bf16_t* wat   = (bf16_t*)(ws + OFF_WAT);
  bf16_t* wqbT  = (bf16_t*)(ws + OFF_WQBT);
  bf16_t* wkvbT = (bf16_t*)(ws + OFF_WKVBT);
  bf16_t* woT   = (bf16_t*)(ws + OFF_WOT);
  float*  qkva  = (float*)(ws + OFF_QKVA);
  bf16_t* qan   = (bf16_t*)(ws + OFF_QAN);
  bf16_t* ckvn  = (bf16_t*)(ws + OFF_CKVN);
  float*  cosT  = (float*)(ws + OFF_COS);
  float*  sinT  = (float*)(ws + OFF_SIN);
  bf16_t* qfull = (bf16_t*)(ws + OFF_QFULL);
  bf16_t* kfull = (bf16_t*)(ws + OFF_KFULL);
  bf16_t* vt    = (bf16_t*)(ws + OFF_VT);
  bf16_t* attn  = (bf16_t*)(ws + OFF_ATTN);

  // conversions / tables
  k_cvt_bf16<<<2048, 256, 0, stream>>>(x, xb, 2048 * 2048);
  k_transpose_cvt<<<dim3(768 / 32, 2048 / 32), 256, 0, stream>>>(w_qa, wat, 2048, 768, 768);
  k_transpose_cvt<<<dim3(640 / 32, 2048 / 32), 256, 0, stream>>>(w_kva, wat + (size_t)768 * 2048, 2048, 576, 640);
  k_transpose_cvt<<<dim3(3072 / 32, 768 / 32), 256, 0, stream>>>(w_qb, wqbT, 768, 3072, 3072);
  k_transpose_cvt<<<dim3(4096 / 32, 512 / 32), 256, 0, stream>>>(w_kvb, wkvbT, 512, 4096, 4096);
  k_transpose_cvt<<<dim3(2048 / 32, 2048 / 32), 256, 0, stream>>>(w_o, woT, 2048, 2048, 2048);
  k_rope_tables<<<2048 * 64 / 256, 256, 0, stream>>>(cosT, sinT);

  // qkv_a = x @ [w_qa | w_kva]   (fp32 out, N=1408)
  k_gemm<0><<<dim3(1408 / 128, 16), 256, 0, stream>>>(xb, wat, 2048, 1408, 2048,
                                                      qkva, nullptr, nullptr, nullptr, nullptr);
  k_rmsnorm_q<<<2048, 256, 0, stream>>>(qkva, qnw, qan);
  k_rmsnorm_kv<<<2048, 256, 0, stream>>>(qkva, kvnw, ckvn, kfull, cosT, sinT);

  // q = qan @ w_qb, fused RoPE -> qfull
  k_gemm<1><<<dim3(3072 / 128, 16), 256, 0, stream>>>(qan, wqbT, 2048, 3072, 768,
                                                      nullptr, qfull, nullptr, cosT, sinT);
  // kv_up = ckvn @ w_kvb -> kfull nope part + vT
  k_gemm<2><<<dim3(4096 / 128, 16), 256, 0, stream>>>(ckvn, wkvbT, 2048, 4096, 512,
                                                      nullptr, kfull, vt, nullptr, nullptr);
  // attention (pair-balanced)
  k_attn<<<dim3(16, 16), 256, 0, stream>>>(qfull, kfull, vt, attn);
  // out = attn @ w_o
  k_gemm<0><<<dim3(2048 / 128, 16), 256, 0, stream>>>(attn, woT, 2048, 2048, 2048,
                                                      out, nullptr, nullptr, nullptr, nullptr);
}

// Round 10
// 340.514 us; speedup vs baseline: 1.8092x; 1.0905x over previous
//
#include <hip/hip_runtime.h>
#include <hip/hip_bf16.h>
#include <stdint.h>

typedef __bf16 bf16_t;
typedef bf16_t bf16x8 __attribute__((ext_vector_type(8)));
typedef bf16_t bf16x4 __attribute__((ext_vector_type(4)));
typedef float  f32x4  __attribute__((ext_vector_type(4)));

#define SLEN 2048
#define NHEAD 16

// ---------------- workspace layout (bytes) ----------------
static const size_t OFF_XB    = 0;          // x bf16            (2048*2048*2 = 8388608)
static const size_t OFF_WAT   = 8388608;    // [w_qa|w_kva]^T    (1408*2048*2 = 5767168)
static const size_t OFF_WQBT  = 14155776;   // w_qb^T            (3072*768*2  = 4718592)
static const size_t OFF_WKVBT = 18874368;   // w_kvb^T           (4096*512*2  = 4194304)
static const size_t OFF_WOT   = 23068672;   // w_o^T             (2048*2048*2 = 8388608)
static const size_t OFF_QKVA  = 31457280;   // qkv_a fp32        (2048*1408*4 = 11534336)
static const size_t OFF_QAN   = 42991616;   // q_a normed bf16   (2048*768*2  = 3145728)
static const size_t OFF_CKVN  = 46137344;   // c_kv normed bf16  (2048*512*2  = 2097152)
static const size_t OFF_COS   = 48234496;   // cos table f32     (2048*64*4   = 524288)
static const size_t OFF_SIN   = 48758784;   // sin table f32     (524288)
static const size_t OFF_QFULL = 49283072;   // q_full bf16 (H,S,192) (12582912)
static const size_t OFF_KFULL = 61865984;   // k_full bf16 (H,S,192) (12582912)
static const size_t OFF_VT    = 74448896;   // v^T bf16 (H,128,S)    (8388608)
static const size_t OFF_ATTN  = 82837504;   // attn out bf16 (S,2048)(8388608)
// total 91,226,112 B

__device__ __forceinline__ void gll16(const void* g, void* l) {
  __builtin_amdgcn_global_load_lds((__attribute__((address_space(1))) void*)g,
                                   (__attribute__((address_space(3))) void*)l,
                                   16, 0, 0);
}

// ---------------- fp32 -> bf16 elementwise ----------------
__global__ __launch_bounds__(256) void k_cvt_bf16(const float* __restrict__ in,
                                                  bf16_t* __restrict__ out, int n) {
  int i = (blockIdx.x * 256 + threadIdx.x) * 8;
  if (i >= n) return;
  f32x4 a = *(const f32x4*)&in[i];
  f32x4 b = *(const f32x4*)&in[i + 4];
  bf16x8 o;
  #pragma unroll
  for (int j = 0; j < 4; j++) { o[j] = (bf16_t)a[j]; o[j + 4] = (bf16_t)b[j]; }
  *(bf16x8*)&out[i] = o;
}

// ---------------- transpose + convert: w(K,N) f32 -> wT(Nout,K) bf16, rows>=N zero ----------------
__global__ __launch_bounds__(256) void k_transpose_cvt(const float* __restrict__ in,
                                                       bf16_t* __restrict__ out,
                                                       int K, int N, int Nout) {
  __shared__ float tile[32][33];
  const int nt = blockIdx.x, kt = blockIdx.y;
  const int t = threadIdx.x;
  const int r = t >> 3, c4 = (t & 7) * 4;
  const int gk = kt * 32 + r;
  #pragma unroll
  for (int j = 0; j < 4; j++) {
    int gn = nt * 32 + c4 + j;
    tile[r][c4 + j] = (gn < N) ? in[(size_t)gk * N + gn] : 0.f;
  }
  __syncthreads();
  bf16x4 o;
  #pragma unroll
  for (int j = 0; j < 4; j++) o[j] = (bf16_t)tile[c4 + j][r];
  *(bf16x4*)&out[(size_t)(nt * 32 + r) * K + kt * 32 + c4] = o;
}

// ---------------- rope tables: cos/sin (S,64) f32 ----------------
__global__ __launch_bounds__(256) void k_rope_tables(float* __restrict__ cosT,
                                                     float* __restrict__ sinT) {
  int i = blockIdx.x * 256 + threadIdx.x;          // S*64 total
  int s = i >> 6, d = i & 63;
  float invf = powf(10000.f, -(float)(2 * (d & 31)) / 64.f);
  float ang = (float)s * invf;
  cosT[i] = cosf(ang);
  sinT[i] = sinf(ang);
}

// ---------------- generic 128x128 bf16 MFMA GEMM, B^T input ----------------
// K-loop: BK=64, double-buffered LDS, ONE barrier per step (prefetch issued at
// step top, drained by the end-of-step barrier after a full step of compute
// cover). LDS XOR-swizzled (byte ^= ((row&7)<<4)): linear gll16 dest +
// inverse-swizzled global source + swizzled ds_read (rule 21; same proven
// pattern as k_attn). Requires K % 64 == 0.
template<int EPI>
__global__ __launch_bounds__(256) void k_gemm(const bf16_t* __restrict__ A,
                                              const bf16_t* __restrict__ Bt,
                                              int M, int N, int K,
                                              float* __restrict__ Cf,
                                              bf16_t* __restrict__ O1,
                                              bf16_t* __restrict__ O2,
                                              const float* __restrict__ cosT,
                                              const float* __restrict__ sinT) {
  __shared__ __align__(16) bf16_t sA[2][128 * 64];   // 2 x 16 KB
  __shared__ __align__(16) bf16_t sB[2][128 * 64];   // 2 x 16 KB
  const int t = threadIdx.x;
  const int lane = t & 63, wave = t >> 6;
  const int l15 = lane & 15, l4 = lane >> 4;
  const int wr = wave >> 1, wc = wave & 1;
  const int rowBase = blockIdx.y * 128, colBase = blockIdx.x * 128;
  const int sswz = (l15 & 7) << 4;   // read-side swizzle (row&7 == l15&7)

  f32x4 acc[4][4] = {};

  // per-thread staging offsets: 4 chunks of 16 B per array per step.
  // linear LDS dest D = i*4096 + t*16 -> row = D>>7, col-byte = D&127;
  // global source element = row*K + ((colb ^ ((row&7)<<4)) >> 1)
  int soff[4];
  #pragma unroll
  for (int i = 0; i < 4; i++) {
    int D = i * 4096 + t * 16;
    int row = D >> 7, cb = D & 127;
    soff[i] = row * K + ((cb ^ ((row & 7) << 4)) >> 1);
  }
  const bf16_t* aBase = A + (size_t)rowBase * K;
  const bf16_t* bBase = Bt + (size_t)colBase * K;

  // prologue: stage step 0 into buf 0
  #pragma unroll
  for (int i = 0; i < 4; i++) {
    gll16(aBase + soff[i], (char*)&sA[0][0] + i * 4096 + t * 16);
    gll16(bBase + soff[i], (char*)&sB[0][0] + i * 4096 + t * 16);
  }
  __syncthreads();

  int cur = 0;
  for (int k0 = 0; k0 < K; k0 += 64) {
    // issue next step's staging first (covered by this step's compute)
    if (k0 + 64 < K) {
      #pragma unroll
      for (int i = 0; i < 4; i++) {
        gll16(aBase + soff[i] + k0 + 64, (char*)&sA[cur ^ 1][0] + i * 4096 + t * 16);
        gll16(bBase + soff[i] + k0 + 64, (char*)&sB[cur ^ 1][0] + i * 4096 + t * 16);
      }
    }
    bf16x8 af[4][2], bfv[4][2];
    #pragma unroll
    for (int ks = 0; ks < 2; ks++) {
      #pragma unroll
      for (int m = 0; m < 4; m++)
        af[m][ks] = *(const bf16x8*)((const char*)&sA[cur][0] +
                      (wr * 64 + m * 16 + l15) * 128 + ((ks * 64 + l4 * 16) ^ sswz));
      #pragma unroll
      for (int n = 0; n < 4; n++)
        bfv[n][ks] = *(const bf16x8*)((const char*)&sB[cur][0] +
                      (wc * 64 + n * 16 + l15) * 128 + ((ks * 64 + l4 * 16) ^ sswz));
    }
    #pragma unroll
    for (int ks = 0; ks < 2; ks++)
      #pragma unroll
      for (int m = 0; m < 4; m++)
        #pragma unroll
        for (int n = 0; n < 4; n++)
          acc[m][n] = __builtin_amdgcn_mfma_f32_16x16x32_bf16(af[m][ks], bfv[n][ks], acc[m][n], 0, 0, 0);
    // single barrier: drains the prefetch and protects buf reuse
    __syncthreads();
    cur ^= 1;
  }

  if (EPI == 0) {
    #pragma unroll
    for (int m = 0; m < 4; m++)
      #pragma unroll
      for (int n = 0; n < 4; n++)
        #pragma unroll
        for (int r = 0; r < 4; r++) {
          int row = rowBase + wr * 64 + m * 16 + l4 * 4 + r;
          int col = colBase + wc * 64 + n * 16 + l15;
          Cf[(size_t)row * N + col] = acc[m][n][r];
        }
  } else if (EPI == 1) {
    #pragma unroll
    for (int m = 0; m < 4; m++)
      #pragma unroll
      for (int n = 0; n < 4; n++) {
        int cb = colBase + wc * 64 + n * 16 + l15;
        int h = cb / 192, d = cb - h * 192;
        #pragma unroll
        for (int r = 0; r < 4; r++) {
          int s = rowBase + wr * 64 + m * 16 + l4 * 4 + r;
          float v = acc[m][n][r];
          float p = __shfl_xor(v, 1);   // pair partner (cols are lane-consecutive)
          float o = v;
          if (d >= 128) {
            int i = d - 128;
            float cs = cosT[s * 64 + i], sn = sinT[s * 64 + i];
            o = (i & 1) ? (v * cs + p * sn) : (v * cs - p * sn);
          }
          O1[((size_t)h * SLEN + s) * 192 + d] = (bf16_t)o;
        }
      }
  } else { // EPI == 2
    #pragma unroll
    for (int m = 0; m < 4; m++)
      #pragma unroll
      for (int n = 0; n < 4; n++) {
        int cb = colBase + wc * 64 + n * 16 + l15;
        int h = cb >> 8, w = cb & 255;
        if (w < 128) {
          #pragma unroll
          for (int r = 0; r < 4; r++) {
            int s = rowBase + wr * 64 + m * 16 + l4 * 4 + r;
            O1[((size_t)h * SLEN + s) * 192 + w] = (bf16_t)acc[m][n][r];
          }
        } else {
          int d = w - 128;
          int s0 = rowBase + wr * 64 + m * 16 + l4 * 4;
          bf16x4 o;
          #pragma unroll
          for (int r = 0; r < 4; r++) o[r] = (bf16_t)acc[m][n][r];
          *(bf16x4*)&O2[((size_t)h * 128 + d) * SLEN + s0] = o;
        }
      }
  }
}

// ---------------- RMSNorm q_a rows (768) -> bf16 ----------------
__global__ __launch_bounds__(256) void k_rmsnorm_q(const float* __restrict__ qkv,
                                                   const float* __restrict__ w,
                                                   bf16_t* __restrict__ out) {
  __shared__ float red[4];
  const int row = blockIdx.x, t = threadIdx.x;
  const float* x = qkv + (size_t)row * 1408;
  float v0 = x[t], v1 = x[t + 256], v2 = x[t + 512];
  float ss = v0 * v0 + v1 * v1 + v2 * v2;
  #pragma unroll
  for (int off = 32; off; off >>= 1) ss += __shfl_down(ss, off);
  if ((t & 63) == 0) red[t >> 6] = ss;
  __syncthreads();
  ss = red[0] + red[1] + red[2] + red[3];
  float rs = rsqrtf(ss * (1.f / 768.f) + 1e-6f);
  out[(size_t)row * 768 + t]       = (bf16_t)(v0 * rs * w[t]);
  out[(size_t)row * 768 + t + 256] = (bf16_t)(v1 * rs * w[t + 256]);
  out[(size_t)row * 768 + t + 512] = (bf16_t)(v2 * rs * w[t + 512]);
}

// ---------------- RMSNorm c_kv rows (512) + k_rope RoPE broadcast ----------------
__global__ __launch_bounds__(256) void k_rmsnorm_kv(const float* __restrict__ qkv,
                                                    const float* __restrict__ w,
                                                    bf16_t* __restrict__ ckvn,
                                                    bf16_t* __restrict__ kfull,
                                                    const float* __restrict__ cosT,
                                                    const float* __restrict__ sinT) {
  __shared__ float red[4];
  const int row = blockIdx.x, t = threadIdx.x;
  const float* x = qkv + (size_t)row * 1408 + 768;
  float v0 = x[t], v1 = x[t + 256];
  float ss = v0 * v0 + v1 * v1;
  #pragma unroll
  for (int off = 32; off; off >>= 1) ss += __shfl_down(ss, off);
  if ((t & 63) == 0) red[t >> 6] = ss;
  __syncthreads();
  ss = red[0] + red[1] + red[2] + red[3];
  float rs = rsqrtf(ss * (1.f / 512.f) + 1e-6f);
  ckvn[(size_t)row * 512 + t]       = (bf16_t)(v0 * rs * w[t]);
  ckvn[(size_t)row * 512 + t + 256] = (bf16_t)(v1 * rs * w[t + 256]);
  if (t < 64) {
    float xv = x[512 + t];
    float xo = x[512 + (t ^ 1)];
    float cs = cosT[row * 64 + t], sn = sinT[row * 64 + t];
    float o = (t & 1) ? (xv * cs + xo * sn) : (xv * cs - xo * sn);
    bf16_t ob = (bf16_t)o;
    for (int h = 0; h < NHEAD; h++)
      kfull[((size_t)h * SLEN + row) * 192 + 128 + t] = ob;
  }
}

// ---------------- causal flash attention, pair-balanced + full double-buffer ----------------
__global__ __launch_bounds__(256) void k_attn(const bf16_t* __restrict__ qfull,
                                              const bf16_t* __restrict__ kfull,
                                              const bf16_t* __restrict__ vT,
                                              bf16_t* __restrict__ out) {
  __shared__ __align__(16) bf16_t sK[2][64 * 192];  // 2 x 24576 B
  __shared__ __align__(16) bf16_t sV[2][128 * 64];  // 2 x 16384 B  [d][kv]
  __shared__ __align__(16) bf16_t P[4][16][72];     // 9216 B per-wave P tiles
  const int bx = blockIdx.x, h = blockIdx.y;
  const int t = threadIdx.x, lane = t & 63, wave = t >> 6;
  const int l15 = lane & 15, l4 = lane >> 4;
  const bf16_t* qh = qfull + (size_t)h * SLEN * 192;
  const bf16_t* kh = kfull + (size_t)h * SLEN * 192;
  const bf16_t* vh = vT + (size_t)h * 128 * SLEN;

  int koff[6];
  #pragma unroll
  for (int i = 0; i < 6; i++) {
    int D = wave * 6144 + i * 1024 + lane * 16;   // linear LDS byte dest
    int row = D / 384, cb = D - row * 384;
    koff[i] = row * 192 + ((cb ^ ((row & 7) << 4)) >> 1);
  }
  int voff[4];
  #pragma unroll
  for (int i = 0; i < 4; i++) {
    int D = wave * 4096 + i * 1024 + lane * 16;
    int row = D >> 7, cb = D & 127;
    voff[i] = row * SLEN + ((cb ^ ((row & 7) << 4)) >> 1);
  }
  const int sswz = (l15 & 7) << 4;   // read-side swizzle (row&7 == l15&7)
  const float scale = 0.0721687836f; // 1/sqrt(192)

  #pragma unroll 1
  for (int ph = 0; ph < 2; ph++) {
    const int qb = ph ? (31 - bx) : bx;
    const int qr0 = qb * 64 + wave * 16;

    bf16x8 qf[6];
    #pragma unroll
    for (int kk = 0; kk < 6; kk++)
      qf[kk] = *(const bf16x8*)&qh[(size_t)(qr0 + l15) * 192 + kk * 32 + l4 * 8];

    f32x4 oacc[8] = {};
    float mrun[4], lrun[4];
    #pragma unroll
    for (int r = 0; r < 4; r++) { mrun[r] = -3e30f; lrun[r] = 0.f; }
    int rowq[4];
    #pragma unroll
    for (int r = 0; r < 4; r++) rowq[r] = qr0 + l4 * 4 + r;

    #pragma unroll
    for (int i = 0; i < 6; i++)
      gll16(kh + koff[i], (char*)&sK[0][0] + wave * 6144 + i * 1024);
    #pragma unroll
    for (int i = 0; i < 4; i++)
      gll16(vh + voff[i], (char*)&sV[0][0] + wave * 4096 + i * 1024);
    __syncthreads();

    int cur = 0;
    for (int kb = 0; kb <= qb; kb++) {
      const int kv0 = kb * 64;
      if (kb < qb) {
        const bf16_t* ksrc = kh + (size_t)(kv0 + 64) * 192;
        #pragma unroll
        for (int i = 0; i < 6; i++)
          gll16(ksrc + koff[i], (char*)&sK[cur ^ 1][0] + wave * 6144 + i * 1024);
        const bf16_t* vsrc = vh + kv0 + 64;
        #pragma unroll
        for (int i = 0; i < 4; i++)
          gll16(vsrc + voff[i], (char*)&sV[cur ^ 1][0] + wave * 4096 + i * 1024);
      }
      f32x4 sc[4] = {};
      #pragma unroll
      for (int kk = 0; kk < 6; kk++)
        #pragma unroll
        for (int n = 0; n < 4; n++) {
          const bf16_t* p = (const bf16_t*)((const char*)&sK[cur][0] +
                              (n * 16 + l15) * 384 + ((kk * 64 + l4 * 16) ^ sswz));
          bf16x8 bv = *(const bf16x8*)p;
          sc[n] = __builtin_amdgcn_mfma_f32_16x16x32_bf16(qf[kk], bv, sc[n], 0, 0, 0);
        }
      float sv[4][4];
      const bool diag = (kb == qb);
      #pragma unroll
      for (int n = 0; n < 4; n++)
        #pragma unroll
        for (int r = 0; r < 4; r++) {
          float v = sc[n][r] * scale;
          if (diag && (kv0 + n * 16 + l15 > rowq[r])) v = -3e30f;
          sv[n][r] = v;
        }
      float fac[4];
      #pragma unroll
      for (int r = 0; r < 4; r++) {
        float rm = fmaxf(fmaxf(sv[0][r], sv[1][r]), fmaxf(sv[2][r], sv[3][r]));
        #pragma unroll
        for (int off = 1; off < 16; off <<= 1) rm = fmaxf(rm, __shfl_xor(rm, off));
        float mn = fmaxf(mrun[r], rm);
        fac[r] = __expf(mrun[r] - mn);
        mrun[r] = mn;
      }
      float psum[4] = {0.f, 0.f, 0.f, 0.f};
      #pragma unroll
      for (int n = 0; n < 4; n++)
        #pragma unroll
        for (int r = 0; r < 4; r++) {
          float p = __expf(sv[n][r] - mrun[r]);
          psum[r] += p;
          P[wave][l4 * 4 + r][n * 16 + l15] = (bf16_t)p;
        }
      #pragma unroll
      for (int r = 0; r < 4; r++) {
        #pragma unroll
        for (int off = 1; off < 16; off <<= 1) psum[r] += __shfl_xor(psum[r], off);
        lrun[r] = lrun[r] * fac[r] + psum[r];
      }
      #pragma unroll
      for (int n8 = 0; n8 < 8; n8++)
        #pragma unroll
        for (int r = 0; r < 4; r++) oacc[n8][r] *= fac[r];
      #pragma unroll
      for (int kk = 0; kk < 2; kk++) {
        bf16x8 pa = *(const bf16x8*)&P[wave][l15][kk * 32 + l4 * 8];
        #pragma unroll
        for (int n8 = 0; n8 < 8; n8++) {
          const bf16_t* p = (const bf16_t*)((const char*)&sV[cur][0] +
                              (n8 * 16 + l15) * 128 + ((kk * 64 + l4 * 16) ^ sswz));
          bf16x8 vb = *(const bf16x8*)p;
          oacc[n8] = __builtin_amdgcn_mfma_f32_16x16x32_bf16(pa, vb, oacc[n8], 0, 0, 0);
        }
      }
      __syncthreads();
      cur ^= 1;
    }

    #pragma unroll
    for (int n8 = 0; n8 < 8; n8++)
      #pragma unroll
      for (int r = 0; r < 4; r++) {
        int s = qr0 + l4 * 4 + r;
        out[(size_t)s * 2048 + h * 128 + n8 * 16 + l15] = (bf16_t)(oacc[n8][r] / lrun[r]);
      }
  }
}

// ---------------- launcher ----------------
extern "C" void kernel_launch(void* const* d_in, const int* in_sizes, int n_in,
                              void* d_out, int out_size, void* d_ws, size_t ws_size,
                              hipStream_t stream) {
  const float* x     = (const float*)d_in[0];
  const float* w_qa  = (const float*)d_in[1];
  const float* qnw   = (const float*)d_in[2];
  const float* w_qb  = (const float*)d_in[3];
  const float* w_kva = (const float*)d_in[4];
  const float* kvnw  = (const float*)d_in[5];
  const float* w_kvb = (const float*)d_in[6];
  const float* w_o   = (const float*)d_in[7];
  float* out = (float*)d_out;
  char* ws = (char*)d_ws;

  bf16_t* xb    = (bf16_t*)(ws + OFF_XB);
  bf16_t* wat   = (bf16_t*)(ws + OFF_WAT);
  bf16_t* wqbT  = (bf16_t*)(ws + OFF_WQBT);
  bf16_t* wkvbT = (bf16_t*)(ws + OFF_WKVBT);
  bf16_t* woT   = (bf16_t*)(ws + OFF_WOT);
  float*  qkva  = (float*)(ws + OFF_QKVA);
  bf16_t* qan   = (bf16_t*)(ws + OFF_QAN);
  bf16_t* ckvn  = (bf16_t*)(ws + OFF_CKVN);
  float*  cosT  = (float*)(ws + OFF_COS);
  float*  sinT  = (float*)(ws + OFF_SIN);
  bf16_t* qfull = (bf16_t*)(ws + OFF_QFULL);
  bf16_t* kfull = (bf16_t*)(ws + OFF_KFULL);
  bf16_t* vt    = (bf16_t*)(ws + OFF_VT);
  bf16_t* attn  = (bf16_t*)(ws + OFF_ATTN);

  // conversions / tables
  k_cvt_bf16<<<2048, 256, 0, stream>>>(x, xb, 2048 * 2048);
  k_transpose_cvt<<<dim3(768 / 32, 2048 / 32), 256, 0, stream>>>(w_qa, wat, 2048, 768, 768);
  k_transpose_cvt<<<dim3(640 / 32, 2048 / 32), 256, 0, stream>>>(w_kva, wat + (size_t)768 * 2048, 2048, 576, 640);
  k_transpose_cvt<<<dim3(3072 / 32, 768 / 32), 256, 0, stream>>>(w_qb, wqbT, 768, 3072, 3072);
  k_transpose_cvt<<<dim3(4096 / 32, 512 / 32), 256, 0, stream>>>(w_kvb, wkvbT, 512, 4096, 4096);
  k_transpose_cvt<<<dim3(2048 / 32, 2048 / 32), 256, 0, stream>>>(w_o, woT, 2048, 2048, 2048);
  k_rope_tables<<<2048 * 64 / 256, 256, 0, stream>>>(cosT, sinT);

  // qkv_a = x @ [w_qa | w_kva]   (fp32 out, N=1408)
  k_gemm<0><<<dim3(1408 / 128, 16), 256, 0, stream>>>(xb, wat, 2048, 1408, 2048,
                                                      qkva, nullptr, nullptr, nullptr, nullptr);
  k_rmsnorm_q<<<2048, 256, 0, stream>>>(qkva, qnw, qan);
  k_rmsnorm_kv<<<2048, 256, 0, stream>>>(qkva, kvnw, ckvn, kfull, cosT, sinT);

  // q = qan @ w_qb, fused RoPE -> qfull
  k_gemm<1><<<dim3(3072 / 128, 16), 256, 0, stream>>>(qan, wqbT, 2048, 3072, 768,
                                                      nullptr, qfull, nullptr, cosT, sinT);
  // kv_up = ckvn @ w_kvb -> kfull nope part + vT
  k_gemm<2><<<dim3(4096 / 128, 16), 256, 0, stream>>>(ckvn, wkvbT, 2048, 4096, 512,
                                                      nullptr, kfull, vt, nullptr, nullptr);
  // attention (pair-balanced)
  k_attn<<<dim3(16, 16), 256, 0, stream>>>(qfull, kfull, vt, attn);
  // out = attn @ w_o
  k_gemm<0><<<dim3(2048 / 128, 16), 256, 0, stream>>>(attn, woT, 2048, 2048, 2048,
                                                      out, nullptr, nullptr, nullptr, nullptr);
}